// Round 3
// baseline (414.725 us; speedup 1.0000x reference)
//
#include <hip/hip_runtime.h>

// FAC dynamic filter + leaky ReLU, fp32 in/out.
// feat:    [N=8, C=64, H=128, W=128] f32
// filters: [N, C*9, H, W] f32, filter channel = c*9 + (kh*3+kw)
// out = leakyrelu_0.2(sum_t feat[h+kh-1, w+kw-1] * filt[c*9+t, h, w])
//
// Memory-bound: ~370 MB unique traffic (filters 302 MB read-once dominant).
// Roofline floor ~59 us at 6.3 TB/s.
// R2: 8 outputs/thread, batched up-front loads per kh (8 x float4 in flight),
// nontemporal loads for read-once filters, nontemporal store for write-once out
// (keep L2 for the 9x-reused feature planes).

#define N_ 8
#define C_ 64
#define H_ 128
#define W_ 128

typedef __attribute__((ext_vector_type(4))) float float4v;

__global__ __launch_bounds__(256) void fac_kernel(
    const float* __restrict__ feat,
    const float* __restrict__ filt,
    float* __restrict__ out)
{
    // idx -> (n, c, h, w8); 16 groups of 8 along w
    int idx = blockIdx.x * 256 + threadIdx.x;
    int w0   = (idx & 15) << 3;      // w8 * 8
    int rest = idx >> 4;
    int h    = rest & (H_ - 1);
    rest   >>= 7;
    int c    = rest & (C_ - 1);
    int n    = rest >> 6;

    const float* fbase = feat + ((n * C_ + c) * H_) * W_;
    const float* wbase = filt + (((n * C_ + c) * 9) * H_ + h) * W_ + w0;

    float acc[8];
    #pragma unroll
    for (int i = 0; i < 8; ++i) acc[i] = 0.f;

    #pragma unroll
    for (int kh = 0; kh < 3; ++kh) {
        const int hh = h + kh - 1;
        const bool valid = (hh >= 0) && (hh < H_);
        const float* row = fbase + (valid ? hh : h) * W_;  // safe dummy addr when invalid

        // --- issue all loads for this kh batch up front (8x float4 + 2 scalars) ---
        const float4v fv0 = *reinterpret_cast<const float4v*>(row + w0);
        const float4v fv1 = *reinterpret_cast<const float4v*>(row + w0 + 4);
        const float  hl0 = (w0 > 0)       ? row[w0 - 1] : 0.f;
        const float  hl1 = (w0 + 8 < W_)  ? row[w0 + 8] : 0.f;

        const float* tb0 = wbase + (kh * 3 + 0) * (H_ * W_);
        const float* tb1 = wbase + (kh * 3 + 1) * (H_ * W_);
        const float* tb2 = wbase + (kh * 3 + 2) * (H_ * W_);
        const float4v wv00 = __builtin_nontemporal_load(reinterpret_cast<const float4v*>(tb0));
        const float4v wv01 = __builtin_nontemporal_load(reinterpret_cast<const float4v*>(tb0) + 1);
        const float4v wv10 = __builtin_nontemporal_load(reinterpret_cast<const float4v*>(tb1));
        const float4v wv11 = __builtin_nontemporal_load(reinterpret_cast<const float4v*>(tb1) + 1);
        const float4v wv20 = __builtin_nontemporal_load(reinterpret_cast<const float4v*>(tb2));
        const float4v wv21 = __builtin_nontemporal_load(reinterpret_cast<const float4v*>(tb2) + 1);

        // --- feature row segment r[0..9] = feat[hh, w0-1 .. w0+8] (0 outside) ---
        float r[10];
        const float vm = valid ? 1.f : 0.f;   // branchless zeroing (avoids divergence)
        r[0] = hl0 * vm;
        #pragma unroll
        for (int i = 0; i < 4; ++i) { r[1 + i] = fv0[i] * vm; r[5 + i] = fv1[i] * vm; }
        r[9] = hl1 * vm;

        #pragma unroll
        for (int j = 0; j < 4; ++j) {
            acc[j]     += r[j]     * wv00[j] + r[j + 1] * wv10[j] + r[j + 2] * wv20[j];
            acc[4 + j] += r[4 + j] * wv01[j] + r[5 + j] * wv11[j] + r[6 + j] * wv21[j];
        }
    }

    float4v o0, o1;
    #pragma unroll
    for (int j = 0; j < 4; ++j) {
        float a0 = acc[j];     o0[j] = (a0 >= 0.f) ? a0 : 0.2f * a0;
        float a1 = acc[4 + j]; o1[j] = (a1 >= 0.f) ? a1 : 0.2f * a1;
    }
    float* optr = out + ((n * C_ + c) * H_ + h) * W_ + w0;
    __builtin_nontemporal_store(o0, reinterpret_cast<float4v*>(optr));
    __builtin_nontemporal_store(o1, reinterpret_cast<float4v*>(optr) + 1);
}

extern "C" void kernel_launch(void* const* d_in, const int* in_sizes, int n_in,
                              void* d_out, int out_size, void* d_ws, size_t ws_size,
                              hipStream_t stream) {
    const float* feat = (const float*)d_in[0];
    const float* filt = (const float*)d_in[1];
    float* out = (float*)d_out;
    const int total_threads = N_ * C_ * H_ * (W_ / 8);   // 1,048,576
    fac_kernel<<<total_threads / 256, 256, 0, stream>>>(feat, filt, out);
}